// Round 10
// baseline (276.284 us; speedup 1.0000x reference)
//
#include <hip/hip_runtime.h>
#include <math.h>

// CircleLoss fused, R10: dense-negatives MFMA kernel + sparse positive pass.
// Stats: ~16 positives/row of 8192 -> dense kernel treats ALL off-diag sims
// as negatives: epilogue = 7 insts/sim (no target loads/compares/selects),
// per-tile col sums to LDS (NO global atomics in the hot loop -- R9 lesson:
// vmcnt is ordered, in-loop atomics put their RTT in the B-load wait path).
// Sparse pass (512 classes, ~140K same-class ordered pairs) adds exp(-logit_p)
// to gP and subtracts the wrongly-added exp(logit_n) from gN, recomputing s
// with block-orientation matched to the dense kernel (error ~1e-6 -> safe).
// Diagonal: masked to 0 in the <=2 diag tiles/block; sparse pass adds its
// (dominant, stationary d/ds) exp(4) term to gP.
// sim = xn @ xn^T, 2-term split-bf16: sim ~= (hiA+loA).hiB (drop A.loB ~2e-4).
// Pairing: panel p + panel 63-p = 65 tiles, 16 blocks/pair -> grid 512 =
// exactly 2 blocks/CU (launch_bounds(512,2): hipcc 2nd arg = min blocks/CU,
// calibrated R7=64/R8=124 VGPR -> cap 128 = the occupancy cliff).
// loss = mean(log1p(sumP*sumN)); fence-free counter finalize (R4-proven).

#define NR    8192
#define DIMK  128
#define NT    64
#define NBLKS 512
#define CCAP  64    // class-member capacity (Poisson(16) > 64: P ~ 1e-20)

typedef __attribute__((ext_vector_type(8))) short short8;
typedef __attribute__((ext_vector_type(4))) float f32x4;

__device__ __forceinline__ unsigned short bf16_rne(float f) {
  uint32_t u = __float_as_uint(f);
  u += 0x7FFFu + ((u >> 16) & 1u);
  return (unsigned short)(u >> 16);
}
__device__ __forceinline__ float b2f(unsigned short h) {
  return __uint_as_float((uint32_t)h << 16);
}

// ws: xhi bf16[NR*DIMK] (2MB) | xlo (2MB) | gP f32[NR] | gN f32[NR] |
//     counter int | pad | cnt int[512] | members int[512*CCAP]

__global__ __launch_bounds__(256) void normalize_split_kernel(
    const float* __restrict__ x, unsigned short* __restrict__ xhi,
    unsigned short* __restrict__ xlo, float* __restrict__ gP,
    float* __restrict__ gN, int* __restrict__ counter, int* __restrict__ cnt) {
  if (blockIdx.x < 32)      gP[blockIdx.x * 256 + threadIdx.x] = 0.f;
  else if (blockIdx.x < 64) gN[(blockIdx.x - 32) * 256 + threadIdx.x] = 0.f;
  if (blockIdx.x == 64 && threadIdx.x == 0) *counter = 0;
  if (blockIdx.x == 65 || blockIdx.x == 66) {
    const int c = (blockIdx.x - 65) * 256 + threadIdx.x;
    if (c < 512) cnt[c] = 0;
  }

  const int wave = threadIdx.x >> 6;
  const int lane = threadIdx.x & 63;
  const int row  = blockIdx.x * 4 + wave;
  const float2 v = ((const float2*)(x + (size_t)row * DIMK))[lane];
  float ss = v.x * v.x + v.y * v.y;
  #pragma unroll
  for (int s = 1; s < 64; s <<= 1) ss += __shfl_xor(ss, s);
  const float r = rsqrtf(ss);
  const float a = v.x * r, b = v.y * r;
  const unsigned short ha = bf16_rne(a), hb = bf16_rne(b);
  const float haf = __uint_as_float((uint32_t)ha << 16);
  const float hbf = __uint_as_float((uint32_t)hb << 16);
  ushort2 hi, lo;
  hi.x = ha; hi.y = hb;
  lo.x = bf16_rne(a - haf); lo.y = bf16_rne(b - hbf);
  ((ushort2*)xhi)[(size_t)row * 64 + lane] = hi;
  ((ushort2*)xlo)[(size_t)row * 64 + lane] = lo;
}

__global__ __launch_bounds__(256) void classbuild_kernel(
    const int* __restrict__ tgt, int* __restrict__ cnt, int* __restrict__ mem) {
  const int row = blockIdx.x * 256 + threadIdx.x;
  const int c = tgt[row];
  const int idx = atomicAdd(&cnt[c], 1);
  if (idx < CCAP) mem[c * CCAP + idx] = row;
}

// Sparse positive pass: one wave per class; 4 ordered pairs per iteration,
// 16 lanes per pair (8 dims each). Orientation matched to the dense kernel:
// the dense value received by row a for partner b used s(o1,o2) with
// o1 = lower 128-block -> recompute exactly that product.
__global__ __launch_bounds__(64) void positive_kernel(
    const unsigned short* __restrict__ xhi, const unsigned short* __restrict__ xlo,
    const int* __restrict__ cnt, const int* __restrict__ mem,
    float* __restrict__ gP, float* __restrict__ gN) {
  const int c = blockIdx.x;
  const int m = min(cnt[c], CCAP);
  const int npairs = m * m;
  const int lane = threadIdx.x;
  const int pr = lane >> 4, sl = lane & 15;
  const int* cm = mem + c * CCAP;

  for (int base = 0; base < npairs; base += 4) {
    const int g = base + pr;
    const bool valid = g < npairs;
    const int gg = valid ? g : 0;
    const int a  = (npairs > 0) ? cm[gg / m] : 0;
    const int b  = (npairs > 0) ? cm[gg % m] : 0;
    const int o1 = ((a >> 7) <= (b >> 7)) ? a : b;
    const int o2 = ((a >> 7) <= (b >> 7)) ? b : a;

    const short8 h1 = *(const short8*)(xhi + (size_t)o1 * DIMK + sl * 8);
    const short8 l1 = *(const short8*)(xlo + (size_t)o1 * DIMK + sl * 8);
    const short8 h2 = *(const short8*)(xhi + (size_t)o2 * DIMK + sl * 8);
    float d = 0.f;
    #pragma unroll
    for (int k = 0; k < 8; ++k)
      d += (b2f((unsigned short)h1[k]) + b2f((unsigned short)l1[k])) *
           b2f((unsigned short)h2[k]);
    #pragma unroll
    for (int sh = 1; sh < 16; sh <<= 1) d += __shfl_xor(d, sh);

    if (valid && sl == 0) {
      const float s = d;
      const float ap = fmaxf(1.25f - s, 0.f);
      const float ep = __expf(ap * fmaf(s, 64.f, -48.f));
      atomicAdd(&gP[a], ep);
      if (a != b) {
        const float t = fmaxf(fmaf(s, 8.f, -2.f), 0.f);  // same formula as dense
        atomicAdd(&gN[a], -__expf(t * t));
      }
    }
  }
}

__global__ __launch_bounds__(512, 2) void simloss_kernel(
    const unsigned short* __restrict__ xhi, const unsigned short* __restrict__ xlo,
    float* __restrict__ gP, float* __restrict__ gN,
    int* __restrict__ counter, float* __restrict__ out) {
  __shared__ float colbuf[5][4][128];   // 10KB: per-tile, per-wy col partials
  __shared__ float red[512];
  __shared__ int islast;

  const int tid  = threadIdx.x;
  const int wave = tid >> 6, lane = tid & 63;
  const int wy = wave & 3, wx = wave >> 2;   // frag grid: 4 row-waves x 2 col-waves
  const int q = lane >> 4, mcol = lane & 15;

  // pairing: 65 tiles/pair, 16 blocks/pair (4-5 tiles), grid 512
  const int p  = blockIdx.x >> 4;
  const int b  = blockIdx.x & 15;
  const int n1 = NT - p;
  const int p2 = NT - 1 - p;
  const int t0 = (b * (NT + 1)) >> 4;
  const int t1 = ((b + 1) * (NT + 1)) >> 4;
  const int ntile = t1 - t0;

  short8 Ah[2][4], Al[2][4];
  auto loadA = [&](int bi) {
    #pragma unroll
    for (int fr = 0; fr < 2; ++fr) {
      const int r = bi * 128 + wy * 32 + fr * 16 + mcol;
      const unsigned short* gh = xhi + (size_t)r * DIMK + q * 8;
      const unsigned short* gl = xlo + (size_t)r * DIMK + q * 8;
      #pragma unroll
      for (int ks = 0; ks < 4; ++ks) {
        Ah[fr][ks] = *(const short8*)(gh + ks * 32);
        Al[fr][ks] = *(const short8*)(gl + ks * 32);
      }
    }
  };

  float rowNa[2][4] = {{0.f}}, rowNb[2][4] = {{0.f}};  // per-panel row sums

  int cur_bi = (t0 < n1) ? p : p2;
  loadA(cur_bi);

  for (int tl = 0; tl < ntile; ++tl) {
    const int ix = t0 + tl;
    const bool in1 = (ix < n1);
    const int bi = in1 ? p : p2;
    const int bj = in1 ? p + ix : p2 + (ix - n1);
    const bool isdiag = in1 ? (ix == 0) : (ix == n1);

    if (bi != cur_bi) { cur_bi = bi; loadA(bi); }

    // ---- MFMA tile: B frags direct global->reg (L1/L2-hot) ----
    f32x4 acc[2][4];
    #pragma unroll
    for (int fr = 0; fr < 2; ++fr)
      #pragma unroll
      for (int fc = 0; fc < 4; ++fc)
        acc[fr][fc] = (f32x4){0.f, 0.f, 0.f, 0.f};
    #pragma unroll
    for (int ks = 0; ks < 4; ++ks) {
      short8 bh[4];
      #pragma unroll
      for (int fc = 0; fc < 4; ++fc) {
        const int rb = bj * 128 + wx * 64 + fc * 16 + mcol;
        bh[fc] = *(const short8*)(xhi + (size_t)rb * DIMK + ks * 32 + q * 8);
      }
      #pragma unroll
      for (int fc = 0; fc < 4; ++fc) {
        acc[0][fc] = __builtin_amdgcn_mfma_f32_16x16x32_bf16(Ah[0][ks], bh[fc], acc[0][fc], 0, 0, 0);
        acc[1][fc] = __builtin_amdgcn_mfma_f32_16x16x32_bf16(Ah[1][ks], bh[fc], acc[1][fc], 0, 0, 0);
        acc[0][fc] = __builtin_amdgcn_mfma_f32_16x16x32_bf16(Al[0][ks], bh[fc], acc[0][fc], 0, 0, 0);
        acc[1][fc] = __builtin_amdgcn_mfma_f32_16x16x32_bf16(Al[1][ks], bh[fc], acc[1][fc], 0, 0, 0);
      }
    }

    // ---- all-negative epilogue (7 insts/sim). C: col=mcol, row=q*4+reg ----
    float cN[4] = {0.f, 0.f, 0.f, 0.f};
    if (!isdiag) {
      #pragma unroll
      for (int fr = 0; fr < 2; ++fr) {
        #pragma unroll
        for (int rg = 0; rg < 4; ++rg) {
          float vn = 0.f;
          #pragma unroll
          for (int fc = 0; fc < 4; ++fc) {
            const float s = acc[fr][fc][rg];
            const float t = fmaxf(fmaf(s, 8.f, -2.f), 0.f);
            const float e = __expf(t * t);   // exp(64*max(s-0.25,0)^2)
            vn += e; cN[fc] += e;
          }
          if (in1) rowNa[fr][rg] += vn; else rowNb[fr][rg] += vn;
        }
      }
    } else {
      #pragma unroll
      for (int fr = 0; fr < 2; ++fr) {
        #pragma unroll
        for (int rg = 0; rg < 4; ++rg) {
          const int rid = wy * 32 + fr * 16 + q * 4 + rg;
          float vn = 0.f;
          #pragma unroll
          for (int fc = 0; fc < 4; ++fc) {
            const int cid = wx * 64 + fc * 16 + mcol;
            const float s = acc[fr][fc][rg];
            const float t = fmaxf(fmaf(s, 8.f, -2.f), 0.f);
            float e = __expf(t * t);
            e = (rid == cid) ? 0.f : e;      // mask diagonal
            vn += e; cN[fc] += e;
          }
          if (in1) rowNa[fr][rg] += vn; else rowNb[fr][rg] += vn;
        }
      }
    }

    // col partials -> LDS (no global atomics in the loop!)
    #pragma unroll
    for (int fc = 0; fc < 4; ++fc) {
      cN[fc] += __shfl_xor(cN[fc], 16);
      cN[fc] += __shfl_xor(cN[fc], 32);
    }
    if (q == 0) {
      #pragma unroll
      for (int fc = 0; fc < 4; ++fc)
        colbuf[tl][wy][wx * 64 + fc * 16 + mcol] = cN[fc];
    }
  }

  __syncthreads();   // all tiles done, colbuf complete

  // ---- end-of-block flushes: fire-and-forget device atomics ----
  for (int t = tid; t < ntile * 128; t += 512) {
    const int tl = t >> 7, col = t & 127;
    const int ix = t0 + tl;
    const bool in1 = (ix < n1);
    const bool dg = in1 ? (ix == 0) : (ix == n1);
    if (!dg) {
      const int bj = in1 ? p + ix : p2 + (ix - n1);
      const float sum = colbuf[tl][0][col] + colbuf[tl][1][col] +
                        colbuf[tl][2][col] + colbuf[tl][3][col];
      atomicAdd(&gN[bj * 128 + col], sum);
    }
  }
  #pragma unroll
  for (int set = 0; set < 2; ++set) {
    const int bi = set ? p2 : p;
    #pragma unroll
    for (int fr = 0; fr < 2; ++fr)
      #pragma unroll
      for (int rg = 0; rg < 4; ++rg) {
        float vn = set ? rowNb[fr][rg] : rowNa[fr][rg];
        #pragma unroll
        for (int m = 1; m < 16; m <<= 1) vn += __shfl_xor(vn, m);
        if (mcol == 0)
          atomicAdd(&gN[bi * 128 + wy * 32 + fr * 16 + q * 4 + rg], vn);
      }
  }

  // ---- fence-free last-block finalize (R4-proven) ----
  __builtin_amdgcn_s_waitcnt(0);   // my atomics ack'd before counter bump
  __syncthreads();
  if (tid == 0) islast = (atomicAdd(counter, 1) == NBLKS - 1) ? 1 : 0;
  __syncthreads();
  if (islast) {
    float local = 0.f;
    #pragma unroll 1
    for (int bb = 0; bb < 2; ++bb) {
      const int base = bb * 4096 + tid * 8;
      float pv[8], nv[8];
      #pragma unroll
      for (int u = 0; u < 8; ++u) pv[u] = atomicAdd(&gP[base + u], 0.0f);
      #pragma unroll
      for (int u = 0; u < 8; ++u) nv[u] = atomicAdd(&gN[base + u], 0.0f);
      #pragma unroll
      for (int u = 0; u < 8; ++u) local += log1pf(pv[u] * nv[u]);
    }
    red[tid] = local;
    __syncthreads();
    for (int s2 = 256; s2 > 0; s2 >>= 1) {
      if (tid < s2) red[tid] += red[tid + s2];
      __syncthreads();
    }
    if (tid == 0) out[0] = red[0] / (float)NR;
  }
}

extern "C" void kernel_launch(void* const* d_in, const int* in_sizes, int n_in,
                              void* d_out, int out_size, void* d_ws, size_t ws_size,
                              hipStream_t stream) {
  const float* x  = (const float*)d_in[0];
  const int* tgt  = (const int*)d_in[1];
  float* out      = (float*)d_out;

  unsigned short* xhi = (unsigned short*)d_ws;
  unsigned short* xlo = xhi + (size_t)NR * DIMK;
  char* base = (char*)d_ws + (size_t)NR * DIMK * 4;   // 4MB
  float* gP = (float*)base;
  float* gN = gP + NR;
  int* counter = (int*)(gN + NR);
  int* cnt = counter + 16;            // 512 ints
  int* mem = cnt + 512;               // 512*CCAP ints

  normalize_split_kernel<<<NR / 4, 256, 0, stream>>>(x, xhi, xlo, gP, gN, counter, cnt);
  classbuild_kernel<<<NR / 256, 256, 0, stream>>>(tgt, cnt, mem);
  positive_kernel<<<512, 64, 0, stream>>>(xhi, xlo, cnt, mem, gP, gN);
  simloss_kernel<<<NBLKS, 512, 0, stream>>>(xhi, xlo, gP, gN, counter, out);
}

// Round 11
// 157.874 us; speedup vs baseline: 1.7500x; 1.7500x over previous
//
#include <hip/hip_runtime.h>
#include <math.h>

// CircleLoss fused, R11 = R10 with the sparse positive pass rebuilt.
// R10 post-mortem: positive_kernel (1 wave/class, 64 serial iters, runtime
// div/mod, IN-LOOP atomics -> vmcnt-ordered RTT per iter) was 152us. R11:
// 256 thr/block = 16 row-slots x 16 lanes; row fragments cached in registers
// (8 dims/lane), one 16B load per pair (lb predicated for orientation match),
// no div/mod, per-row register sums, 2 atomics PER ROW at row end (16K total,
// fire-and-forget).
// Dense kernel (R10-proven, absmax 0.0): treats all off-diag sims as
// negatives, 7-inst epilogue, col sums via LDS, no global atomics in loop,
// no barriers; sparse pass adds exp(-logit_p) to gP and subtracts the
// wrongly-added exp(logit_n) from gN (positive sims here are <=~0.45 ->
// subtraction sensitivity benign; verified R10).
// sim = xn @ xn^T, 2-term split-bf16: sim ~= (hiA+loA).hiB (drop A.loB ~2e-4).
// Pairing: panel p + panel 63-p = 65 tiles, 16 blocks/pair, grid 512 =
// exactly 2 blocks/CU (launch_bounds(512,2); VGPR cap 128 = occupancy cliff).
// loss = mean(log1p(sumP*sumN)); fence-free counter finalize (R4-proven).

#define NR    8192
#define DIMK  128
#define NT    64
#define NBLKS 512
#define CCAP  64    // class-member capacity (Poisson(16) > 64: P ~ 1e-20)

typedef __attribute__((ext_vector_type(8))) short short8;
typedef __attribute__((ext_vector_type(4))) float f32x4;

__device__ __forceinline__ unsigned short bf16_rne(float f) {
  uint32_t u = __float_as_uint(f);
  u += 0x7FFFu + ((u >> 16) & 1u);
  return (unsigned short)(u >> 16);
}
__device__ __forceinline__ float b2f(unsigned short h) {
  return __uint_as_float((uint32_t)h << 16);
}

// ws: xhi bf16[NR*DIMK] (2MB) | xlo (2MB) | gP f32[NR] | gN f32[NR] |
//     counter int | pad | cnt int[512] | members int[512*CCAP]

__global__ __launch_bounds__(256) void normalize_split_kernel(
    const float* __restrict__ x, unsigned short* __restrict__ xhi,
    unsigned short* __restrict__ xlo, float* __restrict__ gP,
    float* __restrict__ gN, int* __restrict__ counter, int* __restrict__ cnt) {
  if (blockIdx.x < 32)      gP[blockIdx.x * 256 + threadIdx.x] = 0.f;
  else if (blockIdx.x < 64) gN[(blockIdx.x - 32) * 256 + threadIdx.x] = 0.f;
  if (blockIdx.x == 64 && threadIdx.x == 0) *counter = 0;
  if (blockIdx.x == 65 || blockIdx.x == 66) {
    const int c = (blockIdx.x - 65) * 256 + threadIdx.x;
    if (c < 512) cnt[c] = 0;
  }

  const int wave = threadIdx.x >> 6;
  const int lane = threadIdx.x & 63;
  const int row  = blockIdx.x * 4 + wave;
  const float2 v = ((const float2*)(x + (size_t)row * DIMK))[lane];
  float ss = v.x * v.x + v.y * v.y;
  #pragma unroll
  for (int s = 1; s < 64; s <<= 1) ss += __shfl_xor(ss, s);
  const float r = rsqrtf(ss);
  const float a = v.x * r, b = v.y * r;
  const unsigned short ha = bf16_rne(a), hb = bf16_rne(b);
  const float haf = __uint_as_float((uint32_t)ha << 16);
  const float hbf = __uint_as_float((uint32_t)hb << 16);
  ushort2 hi, lo;
  hi.x = ha; hi.y = hb;
  lo.x = bf16_rne(a - haf); lo.y = bf16_rne(b - hbf);
  ((ushort2*)xhi)[(size_t)row * 64 + lane] = hi;
  ((ushort2*)xlo)[(size_t)row * 64 + lane] = lo;
}

__global__ __launch_bounds__(256) void classbuild_kernel(
    const int* __restrict__ tgt, int* __restrict__ cnt, int* __restrict__ mem) {
  const int row = blockIdx.x * 256 + threadIdx.x;
  const int c = tgt[row];
  const int idx = atomicAdd(&cnt[c], 1);
  if (idx < CCAP) mem[c * CCAP + idx] = row;
}

// Sparse positive pass: block = one class, 16 row-slots x 16 lanes.
// Row a cached in registers (hi floats + hi+lo floats, 8 dims/lane).
// Per pair: one hb load (+ lb predicated when b is the dense row side),
// dot via 8 fma + 4-level shuffle; accumulate sp/sn in registers; 2 atomics
// per ROW at row end (fire-and-forget).
__global__ __launch_bounds__(256) void positive_kernel(
    const unsigned short* __restrict__ xhi, const unsigned short* __restrict__ xlo,
    const int* __restrict__ cnt, const int* __restrict__ mem,
    float* __restrict__ gP, float* __restrict__ gN) {
  const int c = blockIdx.x;
  const int m = min(cnt[c], CCAP);
  const int slot = threadIdx.x >> 4;   // 0..15
  const int sl   = threadIdx.x & 15;
  const int* cm = mem + c * CCAP;

  for (int i = slot; i < m; i += 16) {
    const int a = cm[i];
    const int ablk = a >> 7;
    const short8 ha = *(const short8*)(xhi + (size_t)a * DIMK + sl * 8);
    const short8 la = *(const short8*)(xlo + (size_t)a * DIMK + sl * 8);
    float haf[8], af[8];
    #pragma unroll
    for (int k = 0; k < 8; ++k) {
      haf[k] = b2f((unsigned short)ha[k]);
      af[k]  = haf[k] + b2f((unsigned short)la[k]);
    }
    float sp = 0.f, sn = 0.f;
    for (int j = 0; j < m; ++j) {
      const int b = cm[j];                    // block-uniform -> scalar load
      const bool aIsRow = (ablk <= (b >> 7)); // dense orientation: o1 = lower block
      const short8 hb = *(const short8*)(xhi + (size_t)b * DIMK + sl * 8);
      float d = 0.f;
      if (aIsRow) {
        #pragma unroll
        for (int k = 0; k < 8; ++k)
          d = fmaf(af[k], b2f((unsigned short)hb[k]), d);
      } else {
        const short8 lb = *(const short8*)(xlo + (size_t)b * DIMK + sl * 8);
        #pragma unroll
        for (int k = 0; k < 8; ++k)
          d = fmaf(haf[k],
                   b2f((unsigned short)hb[k]) + b2f((unsigned short)lb[k]), d);
      }
      #pragma unroll
      for (int sh = 1; sh < 16; sh <<= 1) d += __shfl_xor(d, sh);
      const float s = d;
      const float ap = fmaxf(1.25f - s, 0.f);
      sp += __expf(ap * fmaf(s, 64.f, -48.f));     // exp(-logit_p), incl. diag
      const float t = fmaxf(fmaf(s, 8.f, -2.f), 0.f);
      sn += (a != b) ? __expf(t * t) : 0.f;        // dense's wrongly-added e_n
    }
    if (sl == 0) {
      atomicAdd(&gP[a], sp);
      atomicAdd(&gN[a], -sn);
    }
  }
}

__global__ __launch_bounds__(512, 2) void simloss_kernel(
    const unsigned short* __restrict__ xhi, const unsigned short* __restrict__ xlo,
    float* __restrict__ gP, float* __restrict__ gN,
    int* __restrict__ counter, float* __restrict__ out) {
  __shared__ float colbuf[5][4][128];   // 10KB: per-tile, per-wy col partials
  __shared__ float red[512];
  __shared__ int islast;

  const int tid  = threadIdx.x;
  const int wave = tid >> 6, lane = tid & 63;
  const int wy = wave & 3, wx = wave >> 2;   // frag grid: 4 row-waves x 2 col-waves
  const int q = lane >> 4, mcol = lane & 15;

  // pairing: 65 tiles/pair, 16 blocks/pair (4-5 tiles), grid 512
  const int p  = blockIdx.x >> 4;
  const int b  = blockIdx.x & 15;
  const int n1 = NT - p;
  const int p2 = NT - 1 - p;
  const int t0 = (b * (NT + 1)) >> 4;
  const int t1 = ((b + 1) * (NT + 1)) >> 4;
  const int ntile = t1 - t0;

  short8 Ah[2][4], Al[2][4];
  auto loadA = [&](int bi) {
    #pragma unroll
    for (int fr = 0; fr < 2; ++fr) {
      const int r = bi * 128 + wy * 32 + fr * 16 + mcol;
      const unsigned short* gh = xhi + (size_t)r * DIMK + q * 8;
      const unsigned short* gl = xlo + (size_t)r * DIMK + q * 8;
      #pragma unroll
      for (int ks = 0; ks < 4; ++ks) {
        Ah[fr][ks] = *(const short8*)(gh + ks * 32);
        Al[fr][ks] = *(const short8*)(gl + ks * 32);
      }
    }
  };

  float rowNa[2][4] = {{0.f}}, rowNb[2][4] = {{0.f}};  // per-panel row sums

  int cur_bi = (t0 < n1) ? p : p2;
  loadA(cur_bi);

  for (int tl = 0; tl < ntile; ++tl) {
    const int ix = t0 + tl;
    const bool in1 = (ix < n1);
    const int bi = in1 ? p : p2;
    const int bj = in1 ? p + ix : p2 + (ix - n1);
    const bool isdiag = in1 ? (ix == 0) : (ix == n1);

    if (bi != cur_bi) { cur_bi = bi; loadA(bi); }

    // ---- MFMA tile: B frags direct global->reg (L1/L2-hot) ----
    f32x4 acc[2][4];
    #pragma unroll
    for (int fr = 0; fr < 2; ++fr)
      #pragma unroll
      for (int fc = 0; fc < 4; ++fc)
        acc[fr][fc] = (f32x4){0.f, 0.f, 0.f, 0.f};
    #pragma unroll
    for (int ks = 0; ks < 4; ++ks) {
      short8 bh[4];
      #pragma unroll
      for (int fc = 0; fc < 4; ++fc) {
        const int rb = bj * 128 + wx * 64 + fc * 16 + mcol;
        bh[fc] = *(const short8*)(xhi + (size_t)rb * DIMK + ks * 32 + q * 8);
      }
      #pragma unroll
      for (int fc = 0; fc < 4; ++fc) {
        acc[0][fc] = __builtin_amdgcn_mfma_f32_16x16x32_bf16(Ah[0][ks], bh[fc], acc[0][fc], 0, 0, 0);
        acc[1][fc] = __builtin_amdgcn_mfma_f32_16x16x32_bf16(Ah[1][ks], bh[fc], acc[1][fc], 0, 0, 0);
        acc[0][fc] = __builtin_amdgcn_mfma_f32_16x16x32_bf16(Al[0][ks], bh[fc], acc[0][fc], 0, 0, 0);
        acc[1][fc] = __builtin_amdgcn_mfma_f32_16x16x32_bf16(Al[1][ks], bh[fc], acc[1][fc], 0, 0, 0);
      }
    }

    // ---- all-negative epilogue (7 insts/sim). C: col=mcol, row=q*4+reg ----
    float cN[4] = {0.f, 0.f, 0.f, 0.f};
    if (!isdiag) {
      #pragma unroll
      for (int fr = 0; fr < 2; ++fr) {
        #pragma unroll
        for (int rg = 0; rg < 4; ++rg) {
          float vn = 0.f;
          #pragma unroll
          for (int fc = 0; fc < 4; ++fc) {
            const float s = acc[fr][fc][rg];
            const float t = fmaxf(fmaf(s, 8.f, -2.f), 0.f);
            const float e = __expf(t * t);   // exp(64*max(s-0.25,0)^2)
            vn += e; cN[fc] += e;
          }
          if (in1) rowNa[fr][rg] += vn; else rowNb[fr][rg] += vn;
        }
      }
    } else {
      #pragma unroll
      for (int fr = 0; fr < 2; ++fr) {
        #pragma unroll
        for (int rg = 0; rg < 4; ++rg) {
          const int rid = wy * 32 + fr * 16 + q * 4 + rg;
          float vn = 0.f;
          #pragma unroll
          for (int fc = 0; fc < 4; ++fc) {
            const int cid = wx * 64 + fc * 16 + mcol;
            const float s = acc[fr][fc][rg];
            const float t = fmaxf(fmaf(s, 8.f, -2.f), 0.f);
            float e = __expf(t * t);
            e = (rid == cid) ? 0.f : e;      // mask diagonal
            vn += e; cN[fc] += e;
          }
          if (in1) rowNa[fr][rg] += vn; else rowNb[fr][rg] += vn;
        }
      }
    }

    // col partials -> LDS (no global atomics in the loop!)
    #pragma unroll
    for (int fc = 0; fc < 4; ++fc) {
      cN[fc] += __shfl_xor(cN[fc], 16);
      cN[fc] += __shfl_xor(cN[fc], 32);
    }
    if (q == 0) {
      #pragma unroll
      for (int fc = 0; fc < 4; ++fc)
        colbuf[tl][wy][wx * 64 + fc * 16 + mcol] = cN[fc];
    }
  }

  __syncthreads();   // all tiles done, colbuf complete

  // ---- end-of-block flushes: fire-and-forget device atomics ----
  for (int t = tid; t < ntile * 128; t += 512) {
    const int tl = t >> 7, col = t & 127;
    const int ix = t0 + tl;
    const bool in1 = (ix < n1);
    const bool dg = in1 ? (ix == 0) : (ix == n1);
    if (!dg) {
      const int bj = in1 ? p + ix : p2 + (ix - n1);
      const float sum = colbuf[tl][0][col] + colbuf[tl][1][col] +
                        colbuf[tl][2][col] + colbuf[tl][3][col];
      atomicAdd(&gN[bj * 128 + col], sum);
    }
  }
  #pragma unroll
  for (int set = 0; set < 2; ++set) {
    const int bi = set ? p2 : p;
    #pragma unroll
    for (int fr = 0; fr < 2; ++fr)
      #pragma unroll
      for (int rg = 0; rg < 4; ++rg) {
        float vn = set ? rowNb[fr][rg] : rowNa[fr][rg];
        #pragma unroll
        for (int m = 1; m < 16; m <<= 1) vn += __shfl_xor(vn, m);
        if (mcol == 0)
          atomicAdd(&gN[bi * 128 + wy * 32 + fr * 16 + q * 4 + rg], vn);
      }
  }

  // ---- fence-free last-block finalize (R4-proven) ----
  __builtin_amdgcn_s_waitcnt(0);   // my atomics ack'd before counter bump
  __syncthreads();
  if (tid == 0) islast = (atomicAdd(counter, 1) == NBLKS - 1) ? 1 : 0;
  __syncthreads();
  if (islast) {
    float local = 0.f;
    #pragma unroll 1
    for (int bb = 0; bb < 2; ++bb) {
      const int base = bb * 4096 + tid * 8;
      float pv[8], nv[8];
      #pragma unroll
      for (int u = 0; u < 8; ++u) pv[u] = atomicAdd(&gP[base + u], 0.0f);
      #pragma unroll
      for (int u = 0; u < 8; ++u) nv[u] = atomicAdd(&gN[base + u], 0.0f);
      #pragma unroll
      for (int u = 0; u < 8; ++u) local += log1pf(pv[u] * nv[u]);
    }
    red[tid] = local;
    __syncthreads();
    for (int s2 = 256; s2 > 0; s2 >>= 1) {
      if (tid < s2) red[tid] += red[tid + s2];
      __syncthreads();
    }
    if (tid == 0) out[0] = red[0] / (float)NR;
  }
}

extern "C" void kernel_launch(void* const* d_in, const int* in_sizes, int n_in,
                              void* d_out, int out_size, void* d_ws, size_t ws_size,
                              hipStream_t stream) {
  const float* x  = (const float*)d_in[0];
  const int* tgt  = (const int*)d_in[1];
  float* out      = (float*)d_out;

  unsigned short* xhi = (unsigned short*)d_ws;
  unsigned short* xlo = xhi + (size_t)NR * DIMK;
  char* base = (char*)d_ws + (size_t)NR * DIMK * 4;   // 4MB
  float* gP = (float*)base;
  float* gN = gP + NR;
  int* counter = (int*)(gN + NR);
  int* cnt = counter + 16;            // 512 ints
  int* mem = cnt + 512;               // 512*CCAP ints

  normalize_split_kernel<<<NR / 4, 256, 0, stream>>>(x, xhi, xlo, gP, gN, counter, cnt);
  classbuild_kernel<<<NR / 256, 256, 0, stream>>>(tgt, cnt, mem);
  positive_kernel<<<512, 256, 0, stream>>>(xhi, xlo, cnt, mem, gP, gN);
  simloss_kernel<<<NBLKS, 512, 0, stream>>>(xhi, xlo, gP, gN, counter, out);
}

// Round 12
// 141.137 us; speedup vs baseline: 1.9576x; 1.1186x over previous
//
#include <hip/hip_runtime.h>
#include <math.h>

// CircleLoss fused, R12: dense-negatives MFMA kernel with A panel in LDS.
// R11 post-mortem: VGPR=92 proves the compiler REMATERIALIZED the A-fragment
// global loads inside the tile loop (A-in-registers needs ~145 VGPR > the 128
// cap of 2x512thr blocks) -> ~32 L2-latency loads per tile on the serial
// chain = the 65-70us plateau (R8/R9/R11 choreography changes never touched
// it). Fix: A panel (hi+lo) in LDS, staged once per panel (proven swizzled
// global_load_lds path), A-frags via ds_read_b128 per ks -- low-latency lgkm
// pipe, overlaps B vmem traffic; register demand ~105 < 128 cap, and any
// remat is now a cheap LDS read. No barriers in the tile loop.
// Dense kernel treats all off-diag sims as negatives (7-inst epilogue, col
// sums via LDS, zero in-loop global atomics); sparse positive pass (fused
// into simloss tail, block=class) adds exp(-logit_p) and subtracts the
// wrongly-added exp(logit_n). classbuild fused into normalize (cnt zeroed by
// hipMemsetAsync). 3 dispatches total.
// sim = xn @ xn^T, 2-term split-bf16: sim ~= (hiA+loA).hiB (drop A.loB ~2e-4).
// Pairing: panel p + panel 63-p = 65 tiles, 16 blocks/pair, grid 512 =
// exactly 2 blocks/CU. loss = mean(log1p(sumP*sumN)); fence-free counter
// finalize (R4-proven).

#define NR    8192
#define DIMK  128
#define NT    64
#define NBLKS 512
#define CCAP  64    // class-member capacity (Poisson(16) > 64: P ~ 1e-20)

typedef __attribute__((ext_vector_type(8))) short short8;
typedef __attribute__((ext_vector_type(4))) float f32x4;
typedef __attribute__((address_space(3))) uint32_t lds_u32;
typedef const __attribute__((address_space(1))) uint32_t glb_u32;

__device__ __forceinline__ unsigned short bf16_rne(float f) {
  uint32_t u = __float_as_uint(f);
  u += 0x7FFFu + ((u >> 16) & 1u);
  return (unsigned short)(u >> 16);
}
__device__ __forceinline__ float b2f(unsigned short h) {
  return __uint_as_float((uint32_t)h << 16);
}

// ws: xhi bf16[NR*DIMK] (2MB) | xlo (2MB) | gP f32[NR] | gN f32[NR] |
//     counter int | pad | cnt int[512] | members int[512*CCAP]

__global__ __launch_bounds__(256) void normalize_split_kernel(
    const float* __restrict__ x, const int* __restrict__ tgt,
    unsigned short* __restrict__ xhi, unsigned short* __restrict__ xlo,
    float* __restrict__ gP, float* __restrict__ gN,
    int* __restrict__ counter, int* __restrict__ cnt, int* __restrict__ mem) {
  if (blockIdx.x < 32)      gP[blockIdx.x * 256 + threadIdx.x] = 0.f;
  else if (blockIdx.x < 64) gN[(blockIdx.x - 32) * 256 + threadIdx.x] = 0.f;
  if (blockIdx.x == 64 && threadIdx.x == 0) *counter = 0;

  const int wave = threadIdx.x >> 6;
  const int lane = threadIdx.x & 63;
  const int row  = blockIdx.x * 4 + wave;
  const float2 v = ((const float2*)(x + (size_t)row * DIMK))[lane];
  float ss = v.x * v.x + v.y * v.y;
  #pragma unroll
  for (int s = 1; s < 64; s <<= 1) ss += __shfl_xor(ss, s);
  const float r = rsqrtf(ss);
  const float a = v.x * r, b = v.y * r;
  const unsigned short ha = bf16_rne(a), hb = bf16_rne(b);
  const float haf = __uint_as_float((uint32_t)ha << 16);
  const float hbf = __uint_as_float((uint32_t)hb << 16);
  ushort2 hi, lo;
  hi.x = ha; hi.y = hb;
  lo.x = bf16_rne(a - haf); lo.y = bf16_rne(b - hbf);
  ((ushort2*)xhi)[(size_t)row * 64 + lane] = hi;
  ((ushort2*)xlo)[(size_t)row * 64 + lane] = lo;

  // fused classbuild (cnt pre-zeroed by hipMemsetAsync)
  if (lane == 0) {
    const int c = tgt[row];
    const int idx = atomicAdd(&cnt[c], 1);
    if (idx < CCAP) mem[c * CCAP + idx] = row;
  }
}

__global__ __launch_bounds__(512, 2) void simloss_kernel(
    const unsigned short* __restrict__ xhi, const unsigned short* __restrict__ xlo,
    const int* __restrict__ cnt, const int* __restrict__ mem,
    float* __restrict__ gP, float* __restrict__ gN,
    int* __restrict__ counter, float* __restrict__ out) {
  __shared__ unsigned short AhL[128 * 128];  // 32KB hi panel (swizzled rows)
  __shared__ unsigned short AlL[128 * 128];  // 32KB lo panel
  __shared__ float colbuf[5][4][128];        // 10KB per-tile per-wy col partials
  __shared__ float red[512];
  __shared__ int islast;

  const int tid  = threadIdx.x;
  const int wave = tid >> 6, lane = tid & 63;
  const int wy = wave & 3, wx = wave >> 2;   // frag grid: 4 row-waves x 2 col-waves
  const int q = lane >> 4, mcol = lane & 15;

  // pairing: 65 tiles/pair, 16 blocks/pair (4-5 tiles), grid 512
  const int p  = blockIdx.x >> 4;
  const int b  = blockIdx.x & 15;
  const int n1 = NT - p;
  const int p2 = NT - 1 - p;
  const int t0 = (b * (NT + 1)) >> 4;
  const int t1 = ((b + 1) * (NT + 1)) >> 4;
  const int ntile = t1 - t0;

  // stage A panel (hi+lo) into LDS; swizzle: phys 16B-chunk = c ^ (row&15)
  auto stageA = [&](int bi) {
    const unsigned short* gh = xhi + (size_t)bi * 128 * DIMK;
    const unsigned short* gl = xlo + (size_t)bi * 128 * DIMK;
    #pragma unroll
    for (int g = 0; g < 4; ++g) {
      const int r  = wave * 16 + g * 4 + (lane >> 4);
      const int sc = (lane & 15) ^ (r & 15);
      __builtin_amdgcn_global_load_lds((glb_u32*)(gh + (size_t)r * DIMK + sc * 8),
          (lds_u32*)&AhL[(wave * 16 + g * 4) * 128], 16, 0, 0);
      __builtin_amdgcn_global_load_lds((glb_u32*)(gl + (size_t)r * DIMK + sc * 8),
          (lds_u32*)&AlL[(wave * 16 + g * 4) * 128], 16, 0, 0);
    }
  };

  float rowNa[2][4] = {{0.f}}, rowNb[2][4] = {{0.f}};  // per-panel row sums

  int cur_bi = (t0 < n1) ? p : p2;
  stageA(cur_bi);
  __syncthreads();   // A staged (full vmcnt drain; once per panel)

  for (int tl = 0; tl < ntile; ++tl) {
    const int ix = t0 + tl;
    const bool in1 = (ix < n1);
    const int bi = in1 ? p : p2;
    const int bj = in1 ? p + ix : p2 + (ix - n1);
    const bool isdiag = in1 ? (ix == 0) : (ix == n1);

    if (bi != cur_bi) {        // at most one panel switch per block
      cur_bi = bi;
      __syncthreads();         // all waves done reading old A
      stageA(bi);
      __syncthreads();
    }

    // ---- MFMA tile: A from LDS (lgkm pipe), B direct global (vmem pipe) ----
    f32x4 acc[2][4];
    #pragma unroll
    for (int fr = 0; fr < 2; ++fr)
      #pragma unroll
      for (int fc = 0; fc < 4; ++fc)
        acc[fr][fc] = (f32x4){0.f, 0.f, 0.f, 0.f};
    #pragma unroll
    for (int ks = 0; ks < 4; ++ks) {
      short8 bh[4];
      #pragma unroll
      for (int fc = 0; fc < 4; ++fc) {
        const int rb = bj * 128 + wx * 64 + fc * 16 + mcol;
        bh[fc] = *(const short8*)(xhi + (size_t)rb * DIMK + ks * 32 + q * 8);
      }
      const int pc = (ks * 4 + q) ^ mcol;   // row&15 == mcol
      const int r0 = (wy * 32 + mcol) * 128 + pc * 8;
      const int r1 = (wy * 32 + 16 + mcol) * 128 + pc * 8;
      const short8 ah0 = *(const short8*)&AhL[r0];
      const short8 ah1 = *(const short8*)&AhL[r1];
      const short8 al0 = *(const short8*)&AlL[r0];
      const short8 al1 = *(const short8*)&AlL[r1];
      #pragma unroll
      for (int fc = 0; fc < 4; ++fc) {
        acc[0][fc] = __builtin_amdgcn_mfma_f32_16x16x32_bf16(ah0, bh[fc], acc[0][fc], 0, 0, 0);
        acc[1][fc] = __builtin_amdgcn_mfma_f32_16x16x32_bf16(ah1, bh[fc], acc[1][fc], 0, 0, 0);
        acc[0][fc] = __builtin_amdgcn_mfma_f32_16x16x32_bf16(al0, bh[fc], acc[0][fc], 0, 0, 0);
        acc[1][fc] = __builtin_amdgcn_mfma_f32_16x16x32_bf16(al1, bh[fc], acc[1][fc], 0, 0, 0);
      }
    }

    // ---- all-negative epilogue (R10/R11-proven). C: col=mcol, row=q*4+reg ----
    float cN[4] = {0.f, 0.f, 0.f, 0.f};
    if (!isdiag) {
      #pragma unroll
      for (int fr = 0; fr < 2; ++fr) {
        #pragma unroll
        for (int rg = 0; rg < 4; ++rg) {
          float vn = 0.f;
          #pragma unroll
          for (int fc = 0; fc < 4; ++fc) {
            const float s = acc[fr][fc][rg];
            const float t = fmaxf(fmaf(s, 8.f, -2.f), 0.f);
            const float e = __expf(t * t);   // exp(64*max(s-0.25,0)^2)
            vn += e; cN[fc] += e;
          }
          if (in1) rowNa[fr][rg] += vn; else rowNb[fr][rg] += vn;
        }
      }
    } else {
      #pragma unroll
      for (int fr = 0; fr < 2; ++fr) {
        #pragma unroll
        for (int rg = 0; rg < 4; ++rg) {
          const int rid = wy * 32 + fr * 16 + q * 4 + rg;
          float vn = 0.f;
          #pragma unroll
          for (int fc = 0; fc < 4; ++fc) {
            const int cid = wx * 64 + fc * 16 + mcol;
            const float s = acc[fr][fc][rg];
            const float t = fmaxf(fmaf(s, 8.f, -2.f), 0.f);
            float e = __expf(t * t);
            e = (rid == cid) ? 0.f : e;      // mask diagonal
            vn += e; cN[fc] += e;
          }
          if (in1) rowNa[fr][rg] += vn; else rowNb[fr][rg] += vn;
        }
      }
    }

    // col partials -> LDS (no global atomics in the loop)
    #pragma unroll
    for (int fc = 0; fc < 4; ++fc) {
      cN[fc] += __shfl_xor(cN[fc], 16);
      cN[fc] += __shfl_xor(cN[fc], 32);
    }
    if (q == 0) {
      #pragma unroll
      for (int fc = 0; fc < 4; ++fc)
        colbuf[tl][wy][wx * 64 + fc * 16 + mcol] = cN[fc];
    }
  }

  __syncthreads();   // all tiles done, colbuf complete

  // ---- end-of-block flushes: fire-and-forget device atomics ----
  for (int t = tid; t < ntile * 128; t += 512) {
    const int tl = t >> 7, col = t & 127;
    const int ix = t0 + tl;
    const bool in1 = (ix < n1);
    const bool dg = in1 ? (ix == 0) : (ix == n1);
    if (!dg) {
      const int bj = in1 ? p + ix : p2 + (ix - n1);
      const float sum = colbuf[tl][0][col] + colbuf[tl][1][col] +
                        colbuf[tl][2][col] + colbuf[tl][3][col];
      atomicAdd(&gN[bj * 128 + col], sum);
    }
  }
  #pragma unroll
  for (int set = 0; set < 2; ++set) {
    const int bi = set ? p2 : p;
    #pragma unroll
    for (int fr = 0; fr < 2; ++fr)
      #pragma unroll
      for (int rg = 0; rg < 4; ++rg) {
        float vn = set ? rowNb[fr][rg] : rowNa[fr][rg];
        #pragma unroll
        for (int m = 1; m < 16; m <<= 1) vn += __shfl_xor(vn, m);
        if (mcol == 0)
          atomicAdd(&gN[bi * 128 + wy * 32 + fr * 16 + q * 4 + rg], vn);
      }
  }

  // ---- fused sparse positive pass: this block = class blockIdx.x ----
  // (R11-proven math; 32 row-slots x 16 lanes; atomics fire-and-forget,
  // their latency merges into the finalize drain below.)
  {
    const int c = blockIdx.x;
    const int m = min(cnt[c], CCAP);
    const int slot = tid >> 4;
    const int sl   = tid & 15;
    const int* cm = mem + c * CCAP;
    for (int i = slot; i < m; i += 32) {
      const int a = cm[i];
      const int ablk = a >> 7;
      const short8 ha = *(const short8*)(xhi + (size_t)a * DIMK + sl * 8);
      const short8 la = *(const short8*)(xlo + (size_t)a * DIMK + sl * 8);
      float haf[8], af[8];
      #pragma unroll
      for (int k = 0; k < 8; ++k) {
        haf[k] = b2f((unsigned short)ha[k]);
        af[k]  = haf[k] + b2f((unsigned short)la[k]);
      }
      float sp = 0.f, sn = 0.f;
      for (int j = 0; j < m; ++j) {
        const int bb = cm[j];
        const bool aIsRow = (ablk <= (bb >> 7));  // dense orientation match
        const short8 hb = *(const short8*)(xhi + (size_t)bb * DIMK + sl * 8);
        float d = 0.f;
        if (aIsRow) {
          #pragma unroll
          for (int k = 0; k < 8; ++k)
            d = fmaf(af[k], b2f((unsigned short)hb[k]), d);
        } else {
          const short8 lb = *(const short8*)(xlo + (size_t)bb * DIMK + sl * 8);
          #pragma unroll
          for (int k = 0; k < 8; ++k)
            d = fmaf(haf[k],
                     b2f((unsigned short)hb[k]) + b2f((unsigned short)lb[k]), d);
        }
        #pragma unroll
        for (int sh = 1; sh < 16; sh <<= 1) d += __shfl_xor(d, sh);
        const float s = d;
        const float ap = fmaxf(1.25f - s, 0.f);
        sp += __expf(ap * fmaf(s, 64.f, -48.f));      // exp(-logit_p), incl diag
        const float t = fmaxf(fmaf(s, 8.f, -2.f), 0.f);
        sn += (a != bb) ? __expf(t * t) : 0.f;        // dense's wrongly-added e_n
      }
      if (sl == 0) {
        atomicAdd(&gP[a], sp);
        atomicAdd(&gN[a], -sn);
      }
    }
  }

  // ---- fence-free last-block finalize (R4-proven) ----
  __builtin_amdgcn_s_waitcnt(0);   // my atomics ack'd before counter bump
  __syncthreads();
  if (tid == 0) islast = (atomicAdd(counter, 1) == NBLKS - 1) ? 1 : 0;
  __syncthreads();
  if (islast) {
    float local = 0.f;
    #pragma unroll 1
    for (int bb = 0; bb < 2; ++bb) {
      const int base = bb * 4096 + tid * 8;
      float pv[8], nv[8];
      #pragma unroll
      for (int u = 0; u < 8; ++u) pv[u] = atomicAdd(&gP[base + u], 0.0f);
      #pragma unroll
      for (int u = 0; u < 8; ++u) nv[u] = atomicAdd(&gN[base + u], 0.0f);
      #pragma unroll
      for (int u = 0; u < 8; ++u) local += log1pf(pv[u] * nv[u]);
    }
    red[tid] = local;
    __syncthreads();
    for (int s2 = 256; s2 > 0; s2 >>= 1) {
      if (tid < s2) red[tid] += red[tid + s2];
      __syncthreads();
    }
    if (tid == 0) out[0] = red[0] / (float)NR;
  }
}

extern "C" void kernel_launch(void* const* d_in, const int* in_sizes, int n_in,
                              void* d_out, int out_size, void* d_ws, size_t ws_size,
                              hipStream_t stream) {
  const float* x  = (const float*)d_in[0];
  const int* tgt  = (const int*)d_in[1];
  float* out      = (float*)d_out;

  unsigned short* xhi = (unsigned short*)d_ws;
  unsigned short* xlo = xhi + (size_t)NR * DIMK;
  char* base = (char*)d_ws + (size_t)NR * DIMK * 4;   // 4MB
  float* gP = (float*)base;
  float* gN = gP + NR;
  int* counter = (int*)(gN + NR);
  int* cnt = counter + 16;            // 512 ints
  int* mem = cnt + 512;               // 512*CCAP ints

  hipMemsetAsync(cnt, 0, 512 * sizeof(int), stream);
  normalize_split_kernel<<<NR / 4, 256, 0, stream>>>(x, tgt, xhi, xlo, gP, gN,
                                                     counter, cnt, mem);
  simloss_kernel<<<NBLKS, 512, 0, stream>>>(xhi, xlo, cnt, mem, gP, gN, counter, out);
}